// Round 1
// baseline (263.942 us; speedup 1.0000x reference)
//
#include <hip/hip_runtime.h>
#include <hip/hip_bf16.h>
#include <hip/hip_fp8.h>

// Problem constants (fixed by the reference setup)
#define NN 50000     // nodes
#define NE 800000    // edges
#define FD 128       // feature dim (D_FEAT == DIM_H)
#define NG 512       // graphs
#define NC 10        // classes
#define NL 3         // layers
#define CAP 64       // bucket capacity (deg ~ Poisson(16); max over 50K ~ 33)
#define E1_B 3125    // NE/256 (1 edge/thread)
#define GEMM_B 782   // ceil(3125/4): 4 waves/block, 16 rows/wave
#define CVT_B 128    // (2*FD*FD)/256 weight-convert blocks (layers 1,2 only)
#define FRONT_B 4550 // 5*(GEMM_B+CVT_B); bid%5>0 -> scatter, ==0 -> gemm/cvt

typedef unsigned short u16;
typedef unsigned char u8;
typedef unsigned int u32;
typedef short bf16x8 __attribute__((ext_vector_type(8)));
typedef float f32x4 __attribute__((ext_vector_type(4)));

__device__ __forceinline__ float b2f(u16 v) {
    union { u32 u; float f; } c; c.u = ((u32)v) << 16; return c.f;
}
__device__ __forceinline__ u16 f2b(float f) {
    __hip_bfloat16 h = __float2bfloat16(f);   // RTNE
    return *(u16*)&h;
}
// OCP e4m3 (gfx950 HW cvt). B rows stored fp8 UNSCALED now; dinv applied at
// gather time via per-edge rsqrt(cnt[s]+1). This breaks the cnt->GEMM
// dependency so the x@W0 GEMM fuses into the scatter kernel's idle SIMDs.
__device__ __forceinline__ float p2f(u8 b) {
    __hip_fp8_e4m3 h; h.__x = b; return (float)h;
}
__device__ __forceinline__ u8 f2p(float f) {
    __hip_fp8_e4m3 h(f); return h.__x;
}

// ======== fused front-end: edge scatter + x@W0 GEMM + WT convert ========
// Scatter is at the scattered-4B-store roofline (~0.96 TB/s, VALUBusy 0.4%);
// GEMM blocks (1-in-5 interleave) hide in its idle VALU/MFMA slack.
// GEMM reads W0 as raw fp32 (64KB, L2-hot) -> no LDS, scatter occupancy kept.
// R21 lesson: u16 buckets regressed (scattered 2B stores 0.78 TB/s vs 4B
// 0.95 TB/s); int buckets are optimal.
__global__ __launch_bounds__(256) void k_front(const int* __restrict__ src,
                                               const int* __restrict__ dst,
                                               int* __restrict__ cnt,
                                               int* __restrict__ bkt,
                                               const float* __restrict__ W,
                                               u16* __restrict__ wt,
                                               const float* __restrict__ x,
                                               u8* __restrict__ Bout) {
    const int bid = blockIdx.x;
    const int r5 = bid % 5;
    const int q5 = bid / 5;
    if (r5 != 0) {
        // ---- edge scatter: sid enumerates 0..3639, active < 3125 ----
        const int sid = q5 * 4 + (r5 - 1);
        if (sid >= E1_B) return;
        const int e = sid * 256 + threadIdx.x;        // NE exact
        const int d = dst[e];
        const int slot = atomicAdd(&cnt[d], 1);
        if (slot < CAP) bkt[d * CAP + slot] = src[e]; // guard: OOB-safe
    } else if (q5 < GEMM_B) {
        // ---- gemm0: x(fp32) @ W0 -> B0 (fp8, UNSCALED) ----
        // a_frag: A[m=lane&15][k=q*8+j]; b_frag: W[k][n=ct*16+m];
        // C/D: col=lane&15, row=q*4+reg   [verified m89/m91]
        const int wid = q5 * 4 + (threadIdx.x >> 6);
        if (wid >= 3125) return;
        const int row0 = wid * 16;
        const int lane = threadIdx.x & 63;
        const int m = lane & 15;
        const int q = lane >> 4;
        f32x4 acc[8];
#pragma unroll
        for (int ct = 0; ct < 8; ++ct) acc[ct] = (f32x4){0.f, 0.f, 0.f, 0.f};
        const float* arow = x + (size_t)(row0 + m) * FD + q * 8;
        const float* wbase = W + (size_t)q * 8 * FD + m;
#pragma unroll
        for (int kb = 0; kb < 4; ++kb) {
            const float4 p0 = *(const float4*)(arow + kb * 32);
            const float4 p1 = *(const float4*)(arow + kb * 32 + 4);
            bf16x8 af;
            af[0] = (short)f2b(p0.x); af[1] = (short)f2b(p0.y);
            af[2] = (short)f2b(p0.z); af[3] = (short)f2b(p0.w);
            af[4] = (short)f2b(p1.x); af[5] = (short)f2b(p1.y);
            af[6] = (short)f2b(p1.z); af[7] = (short)f2b(p1.w);
#pragma unroll
            for (int ct = 0; ct < 8; ++ct) {
                const float* wp = wbase + (size_t)kb * 32 * FD + ct * 16;
                bf16x8 bf;
#pragma unroll
                for (int j = 0; j < 8; ++j)
                    bf[j] = (short)f2b(wp[(size_t)j * FD]);
                acc[ct] = __builtin_amdgcn_mfma_f32_16x16x32_bf16(af, bf,
                                                                  acc[ct], 0, 0, 0);
            }
        }
#pragma unroll
        for (int ct = 0; ct < 8; ++ct)
#pragma unroll
            for (int r = 0; r < 4; ++r)
                Bout[(size_t)(row0 + q * 4 + r) * FD + ct * 16 + m] =
                    f2p(acc[ct][r]);
    } else {
        // ---- WT convert, layers 1..2 only (layer 0 read raw above) ----
        const int c = (q5 - GEMM_B) * 256 + threadIdx.x + FD * FD;
        const int l = c >> 14, rr = c & 16383, k = rr >> 7, n = rr & 127;
        wt[(l << 14) + n * FD + k] = f2b(W[c]);
    }
}

// ======== half-wave gather on UNSCALED fp8 rows (bucket CSR) ========
// h[n] = relu(di_n * (sum_in di_s*B[s] + di_n*B[n]) + bias); rows 128 B fp8.
// di_s = rsqrt(cnt[s]+1): 4 broadcast L2 loads + 4 rsqrt per 4-edge iter —
// hidden under the fetch-path-bound row gathers (~2 TB/s, R19).
__device__ __forceinline__ float4 gather_node4(const int rs, const int re,
                                               const int* __restrict__ bkt,
                                               const int* __restrict__ cnt,
                                               const u8* __restrict__ B,
                                               const float di, const int n,
                                               const float4 bb, const int f) {
    const uchar4 vs = *(const uchar4*)(B + (size_t)n * FD + f);
    float a0 = 0.f, a1 = 0.f, a2 = 0.f, a3 = 0.f;
    float b0 = 0.f, b1 = 0.f, b2 = 0.f, b3 = 0.f;
    float c0 = 0.f, c1 = 0.f, c2 = 0.f, c3 = 0.f;
    float d0 = 0.f, d1 = 0.f, d2 = 0.f, d3 = 0.f;
    int e = rs;
    for (; e + 4 <= re; e += 4) {
        const int s0 = bkt[e];
        const int s1 = bkt[e + 1];
        const int s2 = bkt[e + 2];
        const int s3 = bkt[e + 3];
        const float w0 = rsqrtf((float)(cnt[s0] + 1));
        const float w1 = rsqrtf((float)(cnt[s1] + 1));
        const float w2 = rsqrtf((float)(cnt[s2] + 1));
        const float w3 = rsqrtf((float)(cnt[s3] + 1));
        const uchar4 v0 = *(const uchar4*)(B + (size_t)s0 * FD + f);
        const uchar4 v1 = *(const uchar4*)(B + (size_t)s1 * FD + f);
        const uchar4 v2 = *(const uchar4*)(B + (size_t)s2 * FD + f);
        const uchar4 v3 = *(const uchar4*)(B + (size_t)s3 * FD + f);
        a0 = fmaf(w0, p2f(v0.x), a0); a1 = fmaf(w0, p2f(v0.y), a1);
        a2 = fmaf(w0, p2f(v0.z), a2); a3 = fmaf(w0, p2f(v0.w), a3);
        b0 = fmaf(w1, p2f(v1.x), b0); b1 = fmaf(w1, p2f(v1.y), b1);
        b2 = fmaf(w1, p2f(v1.z), b2); b3 = fmaf(w1, p2f(v1.w), b3);
        c0 = fmaf(w2, p2f(v2.x), c0); c1 = fmaf(w2, p2f(v2.y), c1);
        c2 = fmaf(w2, p2f(v2.z), c2); c3 = fmaf(w2, p2f(v2.w), c3);
        d0 = fmaf(w3, p2f(v3.x), d0); d1 = fmaf(w3, p2f(v3.y), d1);
        d2 = fmaf(w3, p2f(v3.z), d2); d3 = fmaf(w3, p2f(v3.w), d3);
    }
    for (; e < re; ++e) {
        const int s0 = bkt[e];
        const float w0 = rsqrtf((float)(cnt[s0] + 1));
        const uchar4 v0 = *(const uchar4*)(B + (size_t)s0 * FD + f);
        a0 = fmaf(w0, p2f(v0.x), a0); a1 = fmaf(w0, p2f(v0.y), a1);
        a2 = fmaf(w0, p2f(v0.z), a2); a3 = fmaf(w0, p2f(v0.w), a3);
    }
    a0 += b0 + c0 + d0 + di * p2f(vs.x);        // self loop: + di_n*B[n]
    a1 += b1 + c1 + d1 + di * p2f(vs.y);
    a2 += b2 + c2 + d2 + di * p2f(vs.z);
    a3 += b3 + c3 + d3 + di * p2f(vs.w);
    float4 r;
    r.x = fmaxf(fmaf(a0, di, bb.x), 0.f);
    r.y = fmaxf(fmaf(a1, di, bb.y), 0.f);
    r.z = fmaxf(fmaf(a2, di, bb.z), 0.f);
    r.w = fmaxf(fmaf(a3, di, bb.w), 0.f);
    return r;
}

// ======== fused gather(l) + gemm(l+1): 512 threads, 8 waves ========
// LDS tile stays bf16 (MFMA input); fp8 only on the global round-trip.
__global__ __launch_bounds__(512) void k_gg(const int* __restrict__ cnt,
                                            const int* __restrict__ bkt,
                                            const u8* __restrict__ Bin,
                                            const float* __restrict__ bias,
                                            const u16* __restrict__ WTn,
                                            u8* __restrict__ Bout) {
    __shared__ u16 sA[16][FD + 8];   // +16B row pad (R12: conflicts 2.8M->0.4M)
    const int tid = threadIdx.x;
    const int wave = tid >> 6;       // 0..7
    const int lane = tid & 63;
    const int nb = blockIdx.x * 16;  // 3125 blocks exact
    {
        const int half = lane >> 5;
        const int n = nb + wave * 2 + half;
        const int f = (lane & 31) * 4;
        const int cn = cnt[n];
        const int rs = n * CAP;
        const float di = rsqrtf((float)(cn + 1));
        const float4 bb = *(const float4*)(bias + f);
        const float4 r = gather_node4(rs, rs + cn, bkt, cnt, Bin, di, n, bb, f);
        ushort4 o;
        o.x = f2b(r.x); o.y = f2b(r.y); o.z = f2b(r.z); o.w = f2b(r.w);
        *(ushort4*)&sA[wave * 2 + half][f] = o;
    }
    __syncthreads();
    const int ct = wave;
    const int m = lane & 15;
    const int q = lane >> 4;
    f32x4 acc = (f32x4){0.f, 0.f, 0.f, 0.f};
    const u16* wrow = WTn + (size_t)m * FD + q * 8 + (size_t)ct * 16 * FD;
#pragma unroll
    for (int kb = 0; kb < 4; ++kb) {
        bf16x8 af = *(const bf16x8*)&sA[m][q * 8 + kb * 32];
        bf16x8 bf = *(const bf16x8*)(wrow + kb * 32);
        acc = __builtin_amdgcn_mfma_f32_16x16x32_bf16(af, bf, acc, 0, 0, 0);
    }
#pragma unroll
    for (int r = 0; r < 4; ++r)
        Bout[(size_t)(nb + q * 4 + r) * FD + ct * 16 + m] = f2p(acc[r]);
}

// ======== fused final gather + mean-pool + head (1024 thr, 1 block/graph) ==
__global__ __launch_bounds__(1024) void k_gpool(const int* __restrict__ cnt,
                                                const int* __restrict__ bkt,
                                                const u8* __restrict__ B,
                                                const float* __restrict__ bias,
                                                const int* __restrict__ batch,
                                                const float* __restrict__ lin_w,
                                                const float* __restrict__ lin_b,
                                                float* __restrict__ out) {
    __shared__ float sfeat[32][FD + 4];   // +4 pad: break 4-way bank aliasing
    __shared__ float hm[FD];
    __shared__ int bnd[2];
    __shared__ float part2[2 * NC];
    const int g = blockIdx.x;                          // NG blocks
    const int tid = threadIdx.x;
    const int lane = tid & 63;
    const int slot = (tid >> 6) * 2 + (lane >> 5);     // 0..31
    const int f = (lane & 31) * 4;
    if (tid < 2) {
        const int key = g + tid;
        int lo = 0, hi = NN;
        while (lo < hi) {
            const int mid = (lo + hi) >> 1;
            if (batch[mid] < key) lo = mid + 1; else hi = mid;
        }
        bnd[tid] = lo;
    }
    __syncthreads();
    const int r0 = bnd[0], r1 = bnd[1];
    const float4 bb = *(const float4*)(bias + f);
    float s0 = 0.f, s1 = 0.f, s2 = 0.f, s3 = 0.f;
    for (int r = r0 + slot; r < r1; r += 32) {
        const int cn = cnt[r];
        const int rs = r * CAP;
        const float di = rsqrtf((float)(cn + 1));
        const float4 v = gather_node4(rs, rs + cn, bkt, cnt, B, di, r, bb, f);
        s0 += v.x; s1 += v.y; s2 += v.z; s3 += v.w;
    }
    sfeat[slot][f] = s0;
    sfeat[slot][f + 1] = s1;
    sfeat[slot][f + 2] = s2;
    sfeat[slot][f + 3] = s3;
    __syncthreads();
    if (tid < 128) {
        float tot = 0.f;
#pragma unroll
        for (int s = 0; s < 32; ++s) tot += sfeat[s][tid];
        const float mean = tot / fmaxf((float)(r1 - r0), 1.0f);
        hm[tid] = mean;
        out[(size_t)g * FD + tid] = mean;
    }
    __syncthreads();
    if (tid < 128) {
        const float hv = hm[tid];
        const int wv = tid >> 6;
#pragma unroll
        for (int c = 0; c < NC; ++c) {
            float p = hv * lin_w[tid * NC + c];
#pragma unroll
            for (int o = 32; o > 0; o >>= 1) p += __shfl_down(p, o, 64);
            if ((tid & 63) == 0) part2[c * 2 + wv] = p;
        }
    }
    __syncthreads();
    if (tid == 0) {
        float lg[NC];
        float m = -1e30f;
#pragma unroll
        for (int c = 0; c < NC; ++c) {
            lg[c] = part2[2 * c] + part2[2 * c + 1] + lin_b[c];
            m = fmaxf(m, lg[c]);
        }
        float s = 0.f;
#pragma unroll
        for (int c = 0; c < NC; ++c) s += expf(lg[c] - m);
        const float lse = m + logf(s);
        float* o = out + (size_t)NG * FD + (size_t)g * NC;
#pragma unroll
        for (int c = 0; c < NC; ++c) o[c] = lg[c] - lse;
    }
}

extern "C" void kernel_launch(void* const* d_in, const int* in_sizes, int n_in,
                              void* d_out, int out_size, void* d_ws, size_t ws_size,
                              hipStream_t stream) {
    const float* x     = (const float*)d_in[0];   // [NN,128] fp32
    const float* W     = (const float*)d_in[1];   // [3,128,128] fp32
    const float* bias  = (const float*)d_in[2];   // [3,128] fp32
    const float* lin_w = (const float*)d_in[3];   // [128,10] fp32
    const float* lin_b = (const float*)d_in[4];   // [10] fp32
    const int*   src   = (const int*)d_in[5];     // edge_index[0], int32
    const int*   dst   = src + NE;                // edge_index[1]
    const int*   batch = (const int*)d_in[6];     // [NN] int32

    // workspace layout (~26 MB), all chunks 16B-aligned
    u8*    B0     = (u8*)d_ws;                        // NN*FD fp8 (unscaled)
    u8*    B1     = B0 + (size_t)NN * FD;             // NN*FD fp8 (unscaled)
    u16*   WT     = (u16*)(B1 + (size_t)NN * FD);     // NL*FD*FD bf16 (transposed; l=0 slot unused)
    int*   bkt    = (int*)(WT + (size_t)NL * FD * FD); // NN*CAP bucket CSR
    int*   cnt    = bkt + (size_t)NN * CAP;           // NN
    float* out    = (float*)d_out;                    // hG [NG*FD] ++ logsm [NG*NC]

    // --- fused front-end: scatter + gemm0 + WT convert in ONE kernel ---
    hipMemsetAsync(cnt, 0, NN * sizeof(int), stream);
    k_front<<<FRONT_B, 256, 0, stream>>>(src, dst, cnt, bkt, W, WT, x, B0);

    // --- layers: fused gather+gemm x2; fused gather+pool+head ---
    k_gg<<<NN / 16, 512, 0, stream>>>(cnt, bkt, B0, bias,
                                      WT + (size_t)1 * FD * FD, B1);
    k_gg<<<NN / 16, 512, 0, stream>>>(cnt, bkt, B1, bias + FD,
                                      WT + (size_t)2 * FD * FD, B0);
    k_gpool<<<NG, 1024, 0, stream>>>(cnt, bkt, B0, bias + 2 * FD,
                                     batch, lin_w, lin_b, out);
}

// Round 2
// 240.941 us; speedup vs baseline: 1.0955x; 1.0955x over previous
//
#include <hip/hip_runtime.h>
#include <hip/hip_bf16.h>
#include <hip/hip_fp8.h>

// Problem constants (fixed by the reference setup)
#define NN 50000     // nodes
#define NE 800000    // edges
#define FD 128       // feature dim (D_FEAT == DIM_H)
#define NG 512       // graphs
#define NC 10        // classes
#define NL 3         // layers
#define CAP 64       // bucket capacity (deg ~ Poisson(16); max over 50K ~ 33)
#define E1_B 3125    // NE/256 (1 edge/thread)
#define GEMM_B 782   // ceil(3125/4): 4 waves/block, 16 rows/wave
#define CVT_B 128    // (2*FD*FD)/256 weight-convert blocks (layers 1,2 only)
#define FRONT_B 4550 // 5*(GEMM_B+CVT_B); bid%5>0 -> scatter, ==0 -> gemm/cvt
#define PATCH_B 12500 // NN*CAP/256

typedef unsigned short u16;
typedef unsigned char u8;
typedef unsigned int u32;
typedef short bf16x8 __attribute__((ext_vector_type(8)));
typedef float f32x4 __attribute__((ext_vector_type(4)));

__device__ __forceinline__ float b2f(u16 v) {
    union { u32 u; float f; } c; c.u = ((u32)v) << 16; return c.f;
}
__device__ __forceinline__ u16 f2b(float f) {
    __hip_bfloat16 h = __float2bfloat16(f);   // RTNE
    return *(u16*)&h;
}
// OCP e4m3 (gfx950 HW cvt). B rows stored fp8 UNSCALED; the edge weight
// dinv[src] is PACKED (bf16) into the high 16 bits of each bucket entry by
// k_patch, so gathers pay ZERO extra loads for normalization. This keeps the
// cnt->GEMM dependency broken (gemm0 fused into the scatter kernel) without
// the round-1 per-edge scattered cnt load + rsqrt latency chain.
__device__ __forceinline__ float p2f(u8 b) {
    __hip_fp8_e4m3 h; h.__x = b; return (float)h;
}
__device__ __forceinline__ u8 f2p(float f) {
    __hip_fp8_e4m3 h(f); return h.__x;
}

// ======== fused front-end: edge scatter + x@W0 GEMM + WT convert ========
// Scatter is at the scattered-4B-store roofline (~0.96 TB/s, VALUBusy 0.4%);
// GEMM blocks (1-in-5 interleave) hide in its idle VALU/MFMA slack.
// GEMM reads W0 as raw fp32 (64KB, L2-hot) -> no LDS, scatter occupancy kept.
// R21 lesson: u16 buckets regressed (scattered 2B stores 0.78 TB/s vs 4B
// 0.95 TB/s); int buckets are optimal.
__global__ __launch_bounds__(256) void k_front(const int* __restrict__ src,
                                               const int* __restrict__ dst,
                                               int* __restrict__ cnt,
                                               int* __restrict__ bkt,
                                               const float* __restrict__ W,
                                               u16* __restrict__ wt,
                                               const float* __restrict__ x,
                                               u8* __restrict__ Bout) {
    const int bid = blockIdx.x;
    const int r5 = bid % 5;
    const int q5 = bid / 5;
    if (r5 != 0) {
        // ---- edge scatter: sid enumerates 0..3639, active < 3125 ----
        const int sid = q5 * 4 + (r5 - 1);
        if (sid >= E1_B) return;
        const int e = sid * 256 + threadIdx.x;        // NE exact
        const int d = dst[e];
        const int slot = atomicAdd(&cnt[d], 1);
        if (slot < CAP) bkt[d * CAP + slot] = src[e]; // guard: OOB-safe
    } else if (q5 < GEMM_B) {
        // ---- gemm0: x(fp32) @ W0 -> B0 (fp8, UNSCALED) ----
        // a_frag: A[m=lane&15][k=q*8+j]; b_frag: W[k][n=ct*16+m];
        // C/D: col=lane&15, row=q*4+reg   [verified m89/m91]
        const int wid = q5 * 4 + (threadIdx.x >> 6);
        if (wid >= 3125) return;
        const int row0 = wid * 16;
        const int lane = threadIdx.x & 63;
        const int m = lane & 15;
        const int q = lane >> 4;
        f32x4 acc[8];
#pragma unroll
        for (int ct = 0; ct < 8; ++ct) acc[ct] = (f32x4){0.f, 0.f, 0.f, 0.f};
        const float* arow = x + (size_t)(row0 + m) * FD + q * 8;
        const float* wbase = W + (size_t)q * 8 * FD + m;
#pragma unroll
        for (int kb = 0; kb < 4; ++kb) {
            const float4 p0 = *(const float4*)(arow + kb * 32);
            const float4 p1 = *(const float4*)(arow + kb * 32 + 4);
            bf16x8 af;
            af[0] = (short)f2b(p0.x); af[1] = (short)f2b(p0.y);
            af[2] = (short)f2b(p0.z); af[3] = (short)f2b(p0.w);
            af[4] = (short)f2b(p1.x); af[5] = (short)f2b(p1.y);
            af[6] = (short)f2b(p1.z); af[7] = (short)f2b(p1.w);
#pragma unroll
            for (int ct = 0; ct < 8; ++ct) {
                const float* wp = wbase + (size_t)kb * 32 * FD + ct * 16;
                bf16x8 bf;
#pragma unroll
                for (int j = 0; j < 8; ++j)
                    bf[j] = (short)f2b(wp[(size_t)j * FD]);
                acc[ct] = __builtin_amdgcn_mfma_f32_16x16x32_bf16(af, bf,
                                                                  acc[ct], 0, 0, 0);
            }
        }
#pragma unroll
        for (int ct = 0; ct < 8; ++ct)
#pragma unroll
            for (int r = 0; r < 4; ++r)
                Bout[(size_t)(row0 + q * 4 + r) * FD + ct * 16 + m] =
                    f2p(acc[ct][r]);
    } else {
        // ---- WT convert, layers 1..2 only (layer 0 read raw above) ----
        const int c = (q5 - GEMM_B) * 256 + threadIdx.x + FD * FD;
        const int l = c >> 14, rr = c & 16383, k = rr >> 7, n = rr & 127;
        wt[(l << 14) + n * FD + k] = f2b(W[c]);
    }
}

// ======== bucket weight patch: entry := src | bf16(dinv[src]) << 16 ========
// Runs after k_front (cnt final). Wave covers exactly one node's 64-slot
// region (CAP*4B = 256B), so cnt[d] is wave-uniform; only the valid prefix
// (avg 16/64 slots) is touched. cnt[v] loads are scattered but hit the
// 200KB L2-resident count array; 12500 blocks hide the latency.
__global__ __launch_bounds__(256) void k_patch(const int* __restrict__ cnt,
                                               int* __restrict__ bkt) {
    const int i = blockIdx.x * 256 + threadIdx.x;   // NN*CAP exact
    const int d = i >> 6;
    const int s = i & 63;
    if (s < cnt[d]) {
        const int v = bkt[i];                       // raw src id (<50000, 16b)
        const u32 w = (u32)f2b(rsqrtf((float)(cnt[v] + 1)));
        bkt[i] = (int)(((u32)v & 0xFFFFu) | (w << 16));
    }
}

// ======== half-wave gather on UNSCALED fp8 rows (packed bucket CSR) ========
// h[n] = relu(di_n * (sum_in w_s*B[s] + di_n*B[n]) + bias); rows 128 B fp8.
// w_s rides in the bucket entry's high 16 bits: unpack = 1 shift + bitcast,
// no extra memory op (round-1 lesson: per-edge scattered cnt+rsqrt chain
// made all gathers latency-bound, gpool 48->60us).
__device__ __forceinline__ float4 gather_node4(const int rs, const int re,
                                               const int* __restrict__ bkt,
                                               const u8* __restrict__ B,
                                               const float di, const int n,
                                               const float4 bb, const int f) {
    const uchar4 vs = *(const uchar4*)(B + (size_t)n * FD + f);
    float a0 = 0.f, a1 = 0.f, a2 = 0.f, a3 = 0.f;
    float b0 = 0.f, b1 = 0.f, b2 = 0.f, b3 = 0.f;
    float c0 = 0.f, c1 = 0.f, c2 = 0.f, c3 = 0.f;
    float d0 = 0.f, d1 = 0.f, d2 = 0.f, d3 = 0.f;
    int e = rs;
    for (; e + 4 <= re; e += 4) {
        const int4 pk = *(const int4*)(bkt + e);   // rs is 16B-aligned (CAP=64)
        const int s0 = pk.x & 0xFFFF;
        const int s1 = pk.y & 0xFFFF;
        const int s2 = pk.z & 0xFFFF;
        const int s3 = pk.w & 0xFFFF;
        const float w0 = b2f((u16)((u32)pk.x >> 16));
        const float w1 = b2f((u16)((u32)pk.y >> 16));
        const float w2 = b2f((u16)((u32)pk.z >> 16));
        const float w3 = b2f((u16)((u32)pk.w >> 16));
        const uchar4 v0 = *(const uchar4*)(B + (size_t)s0 * FD + f);
        const uchar4 v1 = *(const uchar4*)(B + (size_t)s1 * FD + f);
        const uchar4 v2 = *(const uchar4*)(B + (size_t)s2 * FD + f);
        const uchar4 v3 = *(const uchar4*)(B + (size_t)s3 * FD + f);
        a0 = fmaf(w0, p2f(v0.x), a0); a1 = fmaf(w0, p2f(v0.y), a1);
        a2 = fmaf(w0, p2f(v0.z), a2); a3 = fmaf(w0, p2f(v0.w), a3);
        b0 = fmaf(w1, p2f(v1.x), b0); b1 = fmaf(w1, p2f(v1.y), b1);
        b2 = fmaf(w1, p2f(v1.z), b2); b3 = fmaf(w1, p2f(v1.w), b3);
        c0 = fmaf(w2, p2f(v2.x), c0); c1 = fmaf(w2, p2f(v2.y), c1);
        c2 = fmaf(w2, p2f(v2.z), c2); c3 = fmaf(w2, p2f(v2.w), c3);
        d0 = fmaf(w3, p2f(v3.x), d0); d1 = fmaf(w3, p2f(v3.y), d1);
        d2 = fmaf(w3, p2f(v3.z), d2); d3 = fmaf(w3, p2f(v3.w), d3);
    }
    for (; e < re; ++e) {
        const int pk = bkt[e];
        const int s0 = pk & 0xFFFF;
        const float w0 = b2f((u16)((u32)pk >> 16));
        const uchar4 v0 = *(const uchar4*)(B + (size_t)s0 * FD + f);
        a0 = fmaf(w0, p2f(v0.x), a0); a1 = fmaf(w0, p2f(v0.y), a1);
        a2 = fmaf(w0, p2f(v0.z), a2); a3 = fmaf(w0, p2f(v0.w), a3);
    }
    a0 += b0 + c0 + d0 + di * p2f(vs.x);        // self loop: + di_n*B[n]
    a1 += b1 + c1 + d1 + di * p2f(vs.y);
    a2 += b2 + c2 + d2 + di * p2f(vs.z);
    a3 += b3 + c3 + d3 + di * p2f(vs.w);
    float4 r;
    r.x = fmaxf(fmaf(a0, di, bb.x), 0.f);
    r.y = fmaxf(fmaf(a1, di, bb.y), 0.f);
    r.z = fmaxf(fmaf(a2, di, bb.z), 0.f);
    r.w = fmaxf(fmaf(a3, di, bb.w), 0.f);
    return r;
}

// ======== fused gather(l) + gemm(l+1): 512 threads, 8 waves ========
// LDS tile stays bf16 (MFMA input); fp8 only on the global round-trip.
__global__ __launch_bounds__(512) void k_gg(const int* __restrict__ cnt,
                                            const int* __restrict__ bkt,
                                            const u8* __restrict__ Bin,
                                            const float* __restrict__ bias,
                                            const u16* __restrict__ WTn,
                                            u8* __restrict__ Bout) {
    __shared__ u16 sA[16][FD + 8];   // +16B row pad (R12: conflicts 2.8M->0.4M)
    const int tid = threadIdx.x;
    const int wave = tid >> 6;       // 0..7
    const int lane = tid & 63;
    const int nb = blockIdx.x * 16;  // 3125 blocks exact
    {
        const int half = lane >> 5;
        const int n = nb + wave * 2 + half;
        const int f = (lane & 31) * 4;
        const int cn = cnt[n];
        const int rs = n * CAP;
        const float di = rsqrtf((float)(cn + 1));
        const float4 bb = *(const float4*)(bias + f);
        const float4 r = gather_node4(rs, rs + cn, bkt, Bin, di, n, bb, f);
        ushort4 o;
        o.x = f2b(r.x); o.y = f2b(r.y); o.z = f2b(r.z); o.w = f2b(r.w);
        *(ushort4*)&sA[wave * 2 + half][f] = o;
    }
    __syncthreads();
    const int ct = wave;
    const int m = lane & 15;
    const int q = lane >> 4;
    f32x4 acc = (f32x4){0.f, 0.f, 0.f, 0.f};
    const u16* wrow = WTn + (size_t)m * FD + q * 8 + (size_t)ct * 16 * FD;
#pragma unroll
    for (int kb = 0; kb < 4; ++kb) {
        bf16x8 af = *(const bf16x8*)&sA[m][q * 8 + kb * 32];
        bf16x8 bf = *(const bf16x8*)(wrow + kb * 32);
        acc = __builtin_amdgcn_mfma_f32_16x16x32_bf16(af, bf, acc, 0, 0, 0);
    }
#pragma unroll
    for (int r = 0; r < 4; ++r)
        Bout[(size_t)(nb + q * 4 + r) * FD + ct * 16 + m] = f2p(acc[r]);
}

// ======== fused final gather + mean-pool + head (1024 thr, 1 block/graph) ==
__global__ __launch_bounds__(1024) void k_gpool(const int* __restrict__ cnt,
                                                const int* __restrict__ bkt,
                                                const u8* __restrict__ B,
                                                const float* __restrict__ bias,
                                                const int* __restrict__ batch,
                                                const float* __restrict__ lin_w,
                                                const float* __restrict__ lin_b,
                                                float* __restrict__ out) {
    __shared__ float sfeat[32][FD + 4];   // +4 pad: break 4-way bank aliasing
    __shared__ float hm[FD];
    __shared__ int bnd[2];
    __shared__ float part2[2 * NC];
    const int g = blockIdx.x;                          // NG blocks
    const int tid = threadIdx.x;
    const int lane = tid & 63;
    const int slot = (tid >> 6) * 2 + (lane >> 5);     // 0..31
    const int f = (lane & 31) * 4;
    if (tid < 2) {
        const int key = g + tid;
        int lo = 0, hi = NN;
        while (lo < hi) {
            const int mid = (lo + hi) >> 1;
            if (batch[mid] < key) lo = mid + 1; else hi = mid;
        }
        bnd[tid] = lo;
    }
    __syncthreads();
    const int r0 = bnd[0], r1 = bnd[1];
    const float4 bb = *(const float4*)(bias + f);
    float s0 = 0.f, s1 = 0.f, s2 = 0.f, s3 = 0.f;
    for (int r = r0 + slot; r < r1; r += 32) {
        const int cn = cnt[r];
        const int rs = r * CAP;
        const float di = rsqrtf((float)(cn + 1));
        const float4 v = gather_node4(rs, rs + cn, bkt, B, di, r, bb, f);
        s0 += v.x; s1 += v.y; s2 += v.z; s3 += v.w;
    }
    sfeat[slot][f] = s0;
    sfeat[slot][f + 1] = s1;
    sfeat[slot][f + 2] = s2;
    sfeat[slot][f + 3] = s3;
    __syncthreads();
    if (tid < 128) {
        float tot = 0.f;
#pragma unroll
        for (int s = 0; s < 32; ++s) tot += sfeat[s][tid];
        const float mean = tot / fmaxf((float)(r1 - r0), 1.0f);
        hm[tid] = mean;
        out[(size_t)g * FD + tid] = mean;
    }
    __syncthreads();
    if (tid < 128) {
        const float hv = hm[tid];
        const int wv = tid >> 6;
#pragma unroll
        for (int c = 0; c < NC; ++c) {
            float p = hv * lin_w[tid * NC + c];
#pragma unroll
            for (int o = 32; o > 0; o >>= 1) p += __shfl_down(p, o, 64);
            if ((tid & 63) == 0) part2[c * 2 + wv] = p;
        }
    }
    __syncthreads();
    if (tid == 0) {
        float lg[NC];
        float m = -1e30f;
#pragma unroll
        for (int c = 0; c < NC; ++c) {
            lg[c] = part2[2 * c] + part2[2 * c + 1] + lin_b[c];
            m = fmaxf(m, lg[c]);
        }
        float s = 0.f;
#pragma unroll
        for (int c = 0; c < NC; ++c) s += expf(lg[c] - m);
        const float lse = m + logf(s);
        float* o = out + (size_t)NG * FD + (size_t)g * NC;
#pragma unroll
        for (int c = 0; c < NC; ++c) o[c] = lg[c] - lse;
    }
}

extern "C" void kernel_launch(void* const* d_in, const int* in_sizes, int n_in,
                              void* d_out, int out_size, void* d_ws, size_t ws_size,
                              hipStream_t stream) {
    const float* x     = (const float*)d_in[0];   // [NN,128] fp32
    const float* W     = (const float*)d_in[1];   // [3,128,128] fp32
    const float* bias  = (const float*)d_in[2];   // [3,128] fp32
    const float* lin_w = (const float*)d_in[3];   // [128,10] fp32
    const float* lin_b = (const float*)d_in[4];   // [10] fp32
    const int*   src   = (const int*)d_in[5];     // edge_index[0], int32
    const int*   dst   = src + NE;                // edge_index[1]
    const int*   batch = (const int*)d_in[6];     // [NN] int32

    // workspace layout (~26 MB), all chunks 16B-aligned
    u8*    B0     = (u8*)d_ws;                        // NN*FD fp8 (unscaled)
    u8*    B1     = B0 + (size_t)NN * FD;             // NN*FD fp8 (unscaled)
    u16*   WT     = (u16*)(B1 + (size_t)NN * FD);     // NL*FD*FD bf16 (transposed; l=0 slot unused)
    int*   bkt    = (int*)(WT + (size_t)NL * FD * FD); // NN*CAP bucket CSR (packed id|w)
    int*   cnt    = bkt + (size_t)NN * CAP;           // NN
    float* out    = (float*)d_out;                    // hG [NG*FD] ++ logsm [NG*NC]

    // --- fused front-end: scatter + gemm0 + WT convert in ONE kernel ---
    hipMemsetAsync(cnt, 0, NN * sizeof(int), stream);
    k_front<<<FRONT_B, 256, 0, stream>>>(src, dst, cnt, bkt, W, WT, x, B0);
    // --- pack dinv[src] (bf16) into bucket entries' high 16 bits ---
    k_patch<<<PATCH_B, 256, 0, stream>>>(cnt, bkt);

    // --- layers: fused gather+gemm x2; fused gather+pool+head ---
    k_gg<<<NN / 16, 512, 0, stream>>>(cnt, bkt, B0, bias,
                                      WT + (size_t)1 * FD * FD, B1);
    k_gg<<<NN / 16, 512, 0, stream>>>(cnt, bkt, B1, bias + FD,
                                      WT + (size_t)2 * FD * FD, B0);
    k_gpool<<<NG, 1024, 0, stream>>>(cnt, bkt, B0, bias + 2 * FD,
                                     batch, lin_w, lin_b, out);
}

// Round 4
// 228.093 us; speedup vs baseline: 1.1572x; 1.0563x over previous
//
#include <hip/hip_runtime.h>
#include <hip/hip_bf16.h>
#include <hip/hip_fp8.h>

// Problem constants (fixed by the reference setup)
#define NN 50000     // nodes
#define NE 800000    // edges
#define FD 128       // feature dim (D_FEAT == DIM_H)
#define NG 512       // graphs
#define NC 10        // classes
#define NL 3         // layers
#define CAP 64       // bucket capacity (deg ~ Poisson(16); max over 50K ~ 33)
#define E1_B 3125    // NE/256 (1 edge/thread)
#define GEMM_B 782   // ceil(3125/4): 4 waves/block, 16 rows/wave
#define CVT_B 128    // (2*FD*FD)/256 weight-convert blocks (layers 1,2 only)
#define FRONT_B 4550 // 5*(GEMM_B+CVT_B); bid%5>0 -> scatter, ==0 -> gemm/cvt
#define PATCH_B 12500 // NN*CAP/256

typedef unsigned short u16;
typedef unsigned char u8;
typedef unsigned int u32;
typedef short bf16x8 __attribute__((ext_vector_type(8)));
typedef float f32x4 __attribute__((ext_vector_type(4)));
typedef float f32x2 __attribute__((ext_vector_type(2)));

__device__ __forceinline__ float b2f(u16 v) {
    union { u32 u; float f; } c; c.u = ((u32)v) << 16; return c.f;
}
__device__ __forceinline__ u16 f2b(float f) {
    __hip_bfloat16 h = __float2bfloat16(f);   // RTNE
    return *(u16*)&h;
}
// OCP e4m3 (gfx950 HW cvt). B rows stored fp8 UNSCALED; the edge weight
// dinv[src] is PACKED (bf16) into the high 16 bits of each bucket entry by
// k_patch, so gathers pay ZERO extra loads for normalization.
__device__ __forceinline__ float p2f(u8 b) {
    __hip_fp8_e4m3 h; h.__x = b; return (float)h;
}
__device__ __forceinline__ u8 f2p(float f) {
    __hip_fp8_e4m3 h(f); return h.__x;
}

// HW packed fp8->f32 (2 lanes/instr): halves cvt VALU in the gather loops.
// Numerically identical to scalar p2f (both exact fp8->f32). gfx950 native
// fp8 = OCP e4m3fn, matching the f2p encode. NOTE (R3 compile fail): the
// word-select operand is an instruction immediate -> must be a template
// constant, not a runtime bool.
#if defined(__has_builtin)
#if __has_builtin(__builtin_amdgcn_cvt_pk_f32_fp8)
#define HAVE_PKCVT 1
#endif
#endif
template<bool HI>
__device__ __forceinline__ f32x2 pkcvt(u32 u) {
#ifdef HAVE_PKCVT
    return __builtin_amdgcn_cvt_pk_f32_fp8((int)u, HI);
#else
    f32x2 r;
    r[0] = p2f((u8)(HI ? (u >> 16) : u));
    r[1] = p2f((u8)(HI ? (u >> 24) : (u >> 8)));
    return r;
#endif
}

// ======== fused front-end: edge scatter + x@W0 GEMM + WT convert ========
// Scatter is at the scattered-4B-store roofline (R2 counters: WRITE 55MB
// @1.02 TB/s, the measured ceiling); GEMM blocks (1-in-5 interleave) hide in
// its idle VALU/MFMA slack (MfmaUtil 1%, free).
__global__ __launch_bounds__(256) void k_front(const int* __restrict__ src,
                                               const int* __restrict__ dst,
                                               int* __restrict__ cnt,
                                               int* __restrict__ bkt,
                                               const float* __restrict__ W,
                                               u16* __restrict__ wt,
                                               const float* __restrict__ x,
                                               u8* __restrict__ Bout) {
    const int bid = blockIdx.x;
    const int r5 = bid % 5;
    const int q5 = bid / 5;
    if (r5 != 0) {
        // ---- edge scatter: sid enumerates 0..3639, active < 3125 ----
        const int sid = q5 * 4 + (r5 - 1);
        if (sid >= E1_B) return;
        const int e = sid * 256 + threadIdx.x;        // NE exact
        const int d = dst[e];
        const int slot = atomicAdd(&cnt[d], 1);
        if (slot < CAP) bkt[d * CAP + slot] = src[e]; // guard: OOB-safe
    } else if (q5 < GEMM_B) {
        // ---- gemm0: x(fp32) @ W0 -> B0 (fp8, UNSCALED) ----
        // a_frag: A[m=lane&15][k=q*8+j]; b_frag: W[k][n=ct*16+m];
        // C/D: col=lane&15, row=q*4+reg   [verified m89/m91]
        const int wid = q5 * 4 + (threadIdx.x >> 6);
        if (wid >= 3125) return;
        const int row0 = wid * 16;
        const int lane = threadIdx.x & 63;
        const int m = lane & 15;
        const int q = lane >> 4;
        f32x4 acc[8];
#pragma unroll
        for (int ct = 0; ct < 8; ++ct) acc[ct] = (f32x4){0.f, 0.f, 0.f, 0.f};
        const float* arow = x + (size_t)(row0 + m) * FD + q * 8;
        const float* wbase = W + (size_t)q * 8 * FD + m;
#pragma unroll
        for (int kb = 0; kb < 4; ++kb) {
            const float4 p0 = *(const float4*)(arow + kb * 32);
            const float4 p1 = *(const float4*)(arow + kb * 32 + 4);
            bf16x8 af;
            af[0] = (short)f2b(p0.x); af[1] = (short)f2b(p0.y);
            af[2] = (short)f2b(p0.z); af[3] = (short)f2b(p0.w);
            af[4] = (short)f2b(p1.x); af[5] = (short)f2b(p1.y);
            af[6] = (short)f2b(p1.z); af[7] = (short)f2b(p1.w);
#pragma unroll
            for (int ct = 0; ct < 8; ++ct) {
                const float* wp = wbase + (size_t)kb * 32 * FD + ct * 16;
                bf16x8 bf;
#pragma unroll
                for (int j = 0; j < 8; ++j)
                    bf[j] = (short)f2b(wp[(size_t)j * FD]);
                acc[ct] = __builtin_amdgcn_mfma_f32_16x16x32_bf16(af, bf,
                                                                  acc[ct], 0, 0, 0);
            }
        }
#pragma unroll
        for (int ct = 0; ct < 8; ++ct)
#pragma unroll
            for (int r = 0; r < 4; ++r)
                Bout[(size_t)(row0 + q * 4 + r) * FD + ct * 16 + m] =
                    f2p(acc[ct][r]);
    } else {
        // ---- WT convert, layers 1..2 only (layer 0 read raw above) ----
        const int c = (q5 - GEMM_B) * 256 + threadIdx.x + FD * FD;
        const int l = c >> 14, rr = c & 16383, k = rr >> 7, n = rr & 127;
        wt[(l << 14) + n * FD + k] = f2b(W[c]);
    }
}

// ======== bucket weight patch: entry := src | bf16(dinv[src]) << 16 ========
__global__ __launch_bounds__(256) void k_patch(const int* __restrict__ cnt,
                                               int* __restrict__ bkt) {
    const int i = blockIdx.x * 256 + threadIdx.x;   // NN*CAP exact
    const int d = i >> 6;
    const int s = i & 63;
    if (s < cnt[d]) {
        const int v = bkt[i];                       // raw src id (<50000, 16b)
        const u32 w = (u32)f2b(rsqrtf((float)(cnt[v] + 1)));
        bkt[i] = (int)(((u32)v & 0xFFFFu) | (w << 16));
    }
}

// ======== half-wave gather on UNSCALED fp8 rows (packed bucket CSR) ========
// h[n] = relu(di_n * (sum_in w_s*B[s] + di_n*B[n]) + bias); rows 128 B fp8.
// W8: 8 rows in flight (k_gg). k_gpool stays 4-wide: its 1024-thr blocks sit
// at the 2-blocks/CU VGPR cliff (36 VGPR x 8 waves/SIMD = 288 <= 512); the
// 8-wide register footprint would halve gpool occupancy.
template<bool W8>
__device__ __forceinline__ float4 gather_node(const int rs, const int re,
                                              const int* __restrict__ bkt,
                                              const u8* __restrict__ B,
                                              const float di, const int n,
                                              const float4 bb, const int f) {
    const u32 us = *(const u32*)(B + (size_t)n * FD + f);   // self row (early)
    f32x2 aL0 = {0.f, 0.f}, aL1 = {0.f, 0.f}, aL2 = {0.f, 0.f}, aL3 = {0.f, 0.f};
    f32x2 aH0 = {0.f, 0.f}, aH1 = {0.f, 0.f}, aH2 = {0.f, 0.f}, aH3 = {0.f, 0.f};
    int e = rs;
    if (W8) {
        for (; e + 8 <= re; e += 8) {
            const int4 p0 = *(const int4*)(bkt + e);     // rs 16B-aligned
            const int4 p1 = *(const int4*)(bkt + e + 4);
            const u32 r0 = *(const u32*)(B + (size_t)(p0.x & 0xFFFF) * FD + f);
            const u32 r1 = *(const u32*)(B + (size_t)(p0.y & 0xFFFF) * FD + f);
            const u32 r2 = *(const u32*)(B + (size_t)(p0.z & 0xFFFF) * FD + f);
            const u32 r3 = *(const u32*)(B + (size_t)(p0.w & 0xFFFF) * FD + f);
            const u32 r4 = *(const u32*)(B + (size_t)(p1.x & 0xFFFF) * FD + f);
            const u32 r5 = *(const u32*)(B + (size_t)(p1.y & 0xFFFF) * FD + f);
            const u32 r6 = *(const u32*)(B + (size_t)(p1.z & 0xFFFF) * FD + f);
            const u32 r7 = *(const u32*)(B + (size_t)(p1.w & 0xFFFF) * FD + f);
            const float w0 = b2f((u16)((u32)p0.x >> 16));
            const float w1 = b2f((u16)((u32)p0.y >> 16));
            const float w2 = b2f((u16)((u32)p0.z >> 16));
            const float w3 = b2f((u16)((u32)p0.w >> 16));
            const float w4 = b2f((u16)((u32)p1.x >> 16));
            const float w5 = b2f((u16)((u32)p1.y >> 16));
            const float w6 = b2f((u16)((u32)p1.z >> 16));
            const float w7 = b2f((u16)((u32)p1.w >> 16));
            aL0 += pkcvt<false>(r0) * w0; aH0 += pkcvt<true>(r0) * w0;
            aL1 += pkcvt<false>(r1) * w1; aH1 += pkcvt<true>(r1) * w1;
            aL2 += pkcvt<false>(r2) * w2; aH2 += pkcvt<true>(r2) * w2;
            aL3 += pkcvt<false>(r3) * w3; aH3 += pkcvt<true>(r3) * w3;
            aL0 += pkcvt<false>(r4) * w4; aH0 += pkcvt<true>(r4) * w4;
            aL1 += pkcvt<false>(r5) * w5; aH1 += pkcvt<true>(r5) * w5;
            aL2 += pkcvt<false>(r6) * w6; aH2 += pkcvt<true>(r6) * w6;
            aL3 += pkcvt<false>(r7) * w7; aH3 += pkcvt<true>(r7) * w7;
        }
    }
    for (; e + 4 <= re; e += 4) {
        const int4 p0 = *(const int4*)(bkt + e);
        const u32 r0 = *(const u32*)(B + (size_t)(p0.x & 0xFFFF) * FD + f);
        const u32 r1 = *(const u32*)(B + (size_t)(p0.y & 0xFFFF) * FD + f);
        const u32 r2 = *(const u32*)(B + (size_t)(p0.z & 0xFFFF) * FD + f);
        const u32 r3 = *(const u32*)(B + (size_t)(p0.w & 0xFFFF) * FD + f);
        const float w0 = b2f((u16)((u32)p0.x >> 16));
        const float w1 = b2f((u16)((u32)p0.y >> 16));
        const float w2 = b2f((u16)((u32)p0.z >> 16));
        const float w3 = b2f((u16)((u32)p0.w >> 16));
        aL0 += pkcvt<false>(r0) * w0; aH0 += pkcvt<true>(r0) * w0;
        aL1 += pkcvt<false>(r1) * w1; aH1 += pkcvt<true>(r1) * w1;
        aL2 += pkcvt<false>(r2) * w2; aH2 += pkcvt<true>(r2) * w2;
        aL3 += pkcvt<false>(r3) * w3; aH3 += pkcvt<true>(r3) * w3;
    }
    for (; e < re; ++e) {
        const int pk = bkt[e];
        const u32 r0 = *(const u32*)(B + (size_t)(pk & 0xFFFF) * FD + f);
        const float w0 = b2f((u16)((u32)pk >> 16));
        aL0 += pkcvt<false>(r0) * w0; aH0 += pkcvt<true>(r0) * w0;
    }
    aL0 += pkcvt<false>(us) * di;      // self loop: + di_n*B[n]
    aH0 += pkcvt<true>(us) * di;
    const f32x2 L = (aL0 + aL1) + (aL2 + aL3);
    const f32x2 H = (aH0 + aH1) + (aH2 + aH3);
    float4 r;
    r.x = fmaxf(fmaf(L[0], di, bb.x), 0.f);
    r.y = fmaxf(fmaf(L[1], di, bb.y), 0.f);
    r.z = fmaxf(fmaf(H[0], di, bb.z), 0.f);
    r.w = fmaxf(fmaf(H[1], di, bb.w), 0.f);
    return r;
}

// ======== fused gather(l) + gemm(l+1): 512 threads, 8 waves ========
__global__ __launch_bounds__(512) void k_gg(const int* __restrict__ cnt,
                                            const int* __restrict__ bkt,
                                            const u8* __restrict__ Bin,
                                            const float* __restrict__ bias,
                                            const u16* __restrict__ WTn,
                                            u8* __restrict__ Bout) {
    __shared__ u16 sA[16][FD + 8];   // +16B row pad (R12: conflicts 2.8M->0.4M)
    const int tid = threadIdx.x;
    const int wave = tid >> 6;       // 0..7
    const int lane = tid & 63;
    const int nb = blockIdx.x * 16;  // 3125 blocks exact
    {
        const int half = lane >> 5;
        const int n = nb + wave * 2 + half;
        const int f = (lane & 31) * 4;
        const int cn = cnt[n];
        const int rs = n * CAP;
        const float di = rsqrtf((float)(cn + 1));
        const float4 bb = *(const float4*)(bias + f);
        const float4 r = gather_node<true>(rs, rs + cn, bkt, Bin, di, n, bb, f);
        ushort4 o;
        o.x = f2b(r.x); o.y = f2b(r.y); o.z = f2b(r.z); o.w = f2b(r.w);
        *(ushort4*)&sA[wave * 2 + half][f] = o;
    }
    __syncthreads();
    const int ct = wave;
    const int m = lane & 15;
    const int q = lane >> 4;
    f32x4 acc = (f32x4){0.f, 0.f, 0.f, 0.f};
    const u16* wrow = WTn + (size_t)m * FD + q * 8 + (size_t)ct * 16 * FD;
#pragma unroll
    for (int kb = 0; kb < 4; ++kb) {
        bf16x8 af = *(const bf16x8*)&sA[m][q * 8 + kb * 32];
        bf16x8 bf = *(const bf16x8*)(wrow + kb * 32);
        acc = __builtin_amdgcn_mfma_f32_16x16x32_bf16(af, bf, acc, 0, 0, 0);
    }
#pragma unroll
    for (int r = 0; r < 4; ++r)
        Bout[(size_t)(nb + q * 4 + r) * FD + ct * 16 + m] = f2p(acc[r]);
}

// ======== fused final gather + mean-pool + head (1024 thr, 1 block/graph) ==
__global__ __launch_bounds__(1024) void k_gpool(const int* __restrict__ cnt,
                                                const int* __restrict__ bkt,
                                                const u8* __restrict__ B,
                                                const float* __restrict__ bias,
                                                const int* __restrict__ batch,
                                                const float* __restrict__ lin_w,
                                                const float* __restrict__ lin_b,
                                                float* __restrict__ out) {
    __shared__ float sfeat[32][FD + 4];   // +4 pad: break 4-way bank aliasing
    __shared__ float hm[FD];
    __shared__ int bnd[2];
    __shared__ float part2[2 * NC];
    const int g = blockIdx.x;                          // NG blocks
    const int tid = threadIdx.x;
    const int lane = tid & 63;
    const int slot = (tid >> 6) * 2 + (lane >> 5);     // 0..31
    const int f = (lane & 31) * 4;
    if (tid < 2) {
        const int key = g + tid;
        int lo = 0, hi = NN;
        while (lo < hi) {
            const int mid = (lo + hi) >> 1;
            if (batch[mid] < key) lo = mid + 1; else hi = mid;
        }
        bnd[tid] = lo;
    }
    __syncthreads();
    const int r0 = bnd[0], r1 = bnd[1];
    const float4 bb = *(const float4*)(bias + f);
    float s0 = 0.f, s1 = 0.f, s2 = 0.f, s3 = 0.f;
    for (int r = r0 + slot; r < r1; r += 32) {
        const int cn = cnt[r];
        const int rs = r * CAP;
        const float di = rsqrtf((float)(cn + 1));
        const float4 v = gather_node<false>(rs, rs + cn, bkt, B, di, r, bb, f);
        s0 += v.x; s1 += v.y; s2 += v.z; s3 += v.w;
    }
    sfeat[slot][f] = s0;
    sfeat[slot][f + 1] = s1;
    sfeat[slot][f + 2] = s2;
    sfeat[slot][f + 3] = s3;
    __syncthreads();
    if (tid < 128) {
        float tot = 0.f;
#pragma unroll
        for (int s = 0; s < 32; ++s) tot += sfeat[s][tid];
        const float mean = tot / fmaxf((float)(r1 - r0), 1.0f);
        hm[tid] = mean;
        out[(size_t)g * FD + tid] = mean;
    }
    __syncthreads();
    if (tid < 128) {
        const float hv = hm[tid];
        const int wv = tid >> 6;
#pragma unroll
        for (int c = 0; c < NC; ++c) {
            float p = hv * lin_w[tid * NC + c];
#pragma unroll
            for (int o = 32; o > 0; o >>= 1) p += __shfl_down(p, o, 64);
            if ((tid & 63) == 0) part2[c * 2 + wv] = p;
        }
    }
    __syncthreads();
    if (tid == 0) {
        float lg[NC];
        float m = -1e30f;
#pragma unroll
        for (int c = 0; c < NC; ++c) {
            lg[c] = part2[2 * c] + part2[2 * c + 1] + lin_b[c];
            m = fmaxf(m, lg[c]);
        }
        float s = 0.f;
#pragma unroll
        for (int c = 0; c < NC; ++c) s += expf(lg[c] - m);
        const float lse = m + logf(s);
        float* o = out + (size_t)NG * FD + (size_t)g * NC;
#pragma unroll
        for (int c = 0; c < NC; ++c) o[c] = lg[c] - lse;
    }
}

extern "C" void kernel_launch(void* const* d_in, const int* in_sizes, int n_in,
                              void* d_out, int out_size, void* d_ws, size_t ws_size,
                              hipStream_t stream) {
    const float* x     = (const float*)d_in[0];   // [NN,128] fp32
    const float* W     = (const float*)d_in[1];   // [3,128,128] fp32
    const float* bias  = (const float*)d_in[2];   // [3,128] fp32
    const float* lin_w = (const float*)d_in[3];   // [128,10] fp32
    const float* lin_b = (const float*)d_in[4];   // [10] fp32
    const int*   src   = (const int*)d_in[5];     // edge_index[0], int32
    const int*   dst   = src + NE;                // edge_index[1]
    const int*   batch = (const int*)d_in[6];     // [NN] int32

    // workspace layout (~26 MB), all chunks 16B-aligned
    u8*    B0     = (u8*)d_ws;                        // NN*FD fp8 (unscaled)
    u8*    B1     = B0 + (size_t)NN * FD;             // NN*FD fp8 (unscaled)
    u16*   WT     = (u16*)(B1 + (size_t)NN * FD);     // NL*FD*FD bf16 (transposed; l=0 slot unused)
    int*   bkt    = (int*)(WT + (size_t)NL * FD * FD); // NN*CAP bucket CSR (packed id|w)
    int*   cnt    = bkt + (size_t)NN * CAP;           // NN
    float* out    = (float*)d_out;                    // hG [NG*FD] ++ logsm [NG*NC]

    // --- fused front-end: scatter + gemm0 + WT convert in ONE kernel ---
    (void)hipMemsetAsync(cnt, 0, NN * sizeof(int), stream);
    k_front<<<FRONT_B, 256, 0, stream>>>(src, dst, cnt, bkt, W, WT, x, B0);
    // --- pack dinv[src] (bf16) into bucket entries' high 16 bits ---
    k_patch<<<PATCH_B, 256, 0, stream>>>(cnt, bkt);

    // --- layers: fused gather+gemm x2; fused gather+pool+head ---
    k_gg<<<NN / 16, 512, 0, stream>>>(cnt, bkt, B0, bias,
                                      WT + (size_t)1 * FD * FD, B1);
    k_gg<<<NN / 16, 512, 0, stream>>>(cnt, bkt, B1, bias + FD,
                                      WT + (size_t)2 * FD * FD, B0);
    k_gpool<<<NG, 1024, 0, stream>>>(cnt, bkt, B0, bias + 2 * FD,
                                     batch, lin_w, lin_b, out);
}